// Round 1
// baseline (1708.160 us; speedup 1.0000x reference)
//
#include <hip/hip_runtime.h>
#include <cstdint>
#include <cstddef>

// Problem constants
// B=2, S=2048, E=1024, H=16, HD=64; rows = B*S = 4096; heads = B*H = 32.
//
// Scrambled head mapping (faithful TF transpose-reshape):
//   qh[b',h,s',d] = PQ[(d&1)*2048 + (s'&63)*32 + (d>>1) , b'*512 + h*32 + (s'>>6)]
// where PQ = X@W+b, rows r = b*2048+s. We store PT[e][r] (transposed) so the
// gather reads two contiguous 128B chunks per 64-elem head vector.

// ------------------------------------------------------------------
// K1: projection GEMM, stores transposed PT[e*4096 + r] = (X@W)[r,e] + bias[e]
// X: (4096,1024) rm, W: (1024,1024) rm
// ------------------------------------------------------------------
__global__ __launch_bounds__(256) void proj_gemm_t(
    const float* __restrict__ X, const float* __restrict__ W,
    const float* __restrict__ bias, float* __restrict__ PT)
{
    __shared__ float As[16][65];   // [k][r], +1 pad
    __shared__ float Bs[16][68];   // [k][e], +4 pad (16B-aligned rows)
    const int tid = (int)threadIdx.x;
    const int ty = tid & 15;       // r-group (fast -> coalesced transposed store)
    const int tx = tid >> 4;       // e-group
    const int r0 = blockIdx.y * 64;
    const int e0 = blockIdx.x * 64;

    const int lar = tid >> 2;          // A row 0..63
    const int lak = (tid & 3) * 4;     // A k-offset
    const int lbk = tid >> 4;          // B k-row 0..15
    const int lbe = (tid & 15) * 4;    // B e-offset

    float acc[4][4] = {};

    for (int k0 = 0; k0 < 1024; k0 += 16) {
        float4 av = *(const float4*)(X + (size_t)(r0 + lar) * 1024 + k0 + lak);
        float4 bv = *(const float4*)(W + (size_t)(k0 + lbk) * 1024 + e0 + lbe);
        __syncthreads();
        As[lak+0][lar] = av.x; As[lak+1][lar] = av.y;
        As[lak+2][lar] = av.z; As[lak+3][lar] = av.w;
        Bs[lbk][lbe+0] = bv.x; Bs[lbk][lbe+1] = bv.y;
        Bs[lbk][lbe+2] = bv.z; Bs[lbk][lbe+3] = bv.w;
        __syncthreads();
        #pragma unroll
        for (int kk = 0; kk < 16; ++kk) {
            float a[4], b[4];
            #pragma unroll
            for (int i = 0; i < 4; ++i) a[i] = As[kk][ty*4+i];
            #pragma unroll
            for (int j = 0; j < 4; ++j) b[j] = Bs[kk][tx*4+j];
            #pragma unroll
            for (int i = 0; i < 4; ++i)
                #pragma unroll
                for (int j = 0; j < 4; ++j)
                    acc[i][j] += a[i] * b[j];
        }
    }
    #pragma unroll
    for (int j = 0; j < 4; ++j) {
        float bb = bias[e0 + tx*4 + j];
        float4 v = make_float4(acc[0][j]+bb, acc[1][j]+bb, acc[2][j]+bb, acc[3][j]+bb);
        *(float4*)(PT + (size_t)(e0 + tx*4 + j) * 4096 + r0 + ty*4) = v;
    }
}

// ------------------------------------------------------------------
// K2: gather scrambled heads from PT, optional L2-normalize.
// Out[(head*2048 + s')*64 + d], one wave per head-vector.
// ------------------------------------------------------------------
__global__ __launch_bounds__(256) void gather_heads(
    const float* __restrict__ PT, float* __restrict__ Out, int do_norm)
{
    const int tid  = (int)threadIdx.x;
    const int lane = tid & 63;
    const int vec  = blockIdx.x * 4 + (tid >> 6);   // 0..65535
    const int head = vec >> 11;                     // 0..31 (b'*16+h)
    const int sp   = vec & 2047;                    // s'
    const int c    = (head >> 4) * 512 + (head & 15) * 32 + (sp >> 6);
    const int src  = (lane & 1) * 2048 + (sp & 63) * 32 + (lane >> 1);
    float v = PT[(size_t)c * 4096 + src];
    if (do_norm) {
        float ss = v * v;
        #pragma unroll
        for (int mk = 32; mk >= 1; mk >>= 1) ss += __shfl_xor(ss, mk);
        v = v / sqrtf(ss);
    }
    Out[(size_t)vec * 64 + lane] = v;
}

// ------------------------------------------------------------------
// K3: causal attention per (i-tile 64 rows, head).
// logits = (qn.kn)*1000, masked j>i -> -1e9; softmax; write attn (fp32, full
// 2048 cols incl. zeros); accumulate z = attn @ V.
// Two passes: pass1 online (m,l); pass2 recompute S, write attn, z-update.
// ------------------------------------------------------------------
__global__ __launch_bounds__(256) void attn_kernel(
    const float* __restrict__ Qn, const float* __restrict__ Kn,
    const float* __restrict__ Vh, float* __restrict__ Attn,
    float* __restrict__ Z)
{
    const int it   = blockIdx.x;    // 0..31
    const int head = blockIdx.y;    // 0..31
    const int tid  = (int)threadIdx.x;
    const int tx = tid & 15;        // j/d-group (fast -> coalesced attn/z store)
    const int ty = tid >> 4;        // i-group
    const int i0 = it * 64;

    const float* __restrict__ Qh = Qn + (size_t)head * (2048*64);
    const float* __restrict__ Kh = Kn + (size_t)head * (2048*64);
    const float* __restrict__ Vv = Vh + (size_t)head * (2048*64);
    float* __restrict__ Ah = Attn + (size_t)head * ((size_t)2048*2048);

    __shared__ float qs[64][68];  // transposed: qs[d][i]
    __shared__ float kb[64][68];  // transposed k: kb[d][j]; reused as attn ab[i][j]
    __shared__ float vb[64][68];  // natural: vb[j][d]

    const int lr = tid >> 2;          // row 0..63
    const int lc = (tid & 3) * 4;     // col base (x4 over q-steps of 16)

    // Q tile -> qs (transposed)
    #pragma unroll
    for (int q = 0; q < 4; ++q) {
        const int col = lc + q * 16;
        float4 t = *(const float4*)(Qh + (size_t)(i0 + lr) * 64 + col);
        qs[col+0][lr] = t.x; qs[col+1][lr] = t.y;
        qs[col+2][lr] = t.z; qs[col+3][lr] = t.w;
    }

    float m[4], l[4];
    #pragma unroll
    for (int i = 0; i < 4; ++i) { m[i] = -3.0e38f; l[i] = 0.0f; }

    // ---------- pass 1: online row max & expsum ----------
    for (int jt = 0; jt <= it; ++jt) {
        __syncthreads();
        #pragma unroll
        for (int q = 0; q < 4; ++q) {
            const int col = lc + q * 16;
            float4 t = *(const float4*)(Kh + (size_t)(jt*64 + lr) * 64 + col);
            kb[col+0][lr] = t.x; kb[col+1][lr] = t.y;
            kb[col+2][lr] = t.z; kb[col+3][lr] = t.w;
        }
        __syncthreads();

        float s[4][4] = {};
        #pragma unroll 8
        for (int d = 0; d < 64; ++d) {
            float4 a = *(const float4*)&qs[d][ty*4];
            float4 b = *(const float4*)&kb[d][tx*4];
            float av[4] = {a.x, a.y, a.z, a.w};
            float bv[4] = {b.x, b.y, b.z, b.w};
            #pragma unroll
            for (int ii = 0; ii < 4; ++ii)
                #pragma unroll
                for (int jj = 0; jj < 4; ++jj)
                    s[ii][jj] += av[ii] * bv[jj];
        }
        const bool diag = (jt == it);
        #pragma unroll
        for (int ii = 0; ii < 4; ++ii) {
            float sl[4];
            #pragma unroll
            for (int jj = 0; jj < 4; ++jj) {
                float lv = s[ii][jj] * 1000.0f;
                if (diag && (tx*4+jj > ty*4+ii)) lv = -1.0e9f;
                sl[jj] = lv;
            }
            float mt = fmaxf(fmaxf(sl[0], sl[1]), fmaxf(sl[2], sl[3]));
            float mn = fmaxf(m[ii], mt);
            l[ii] = l[ii] * __expf(m[ii] - mn)
                  + __expf(sl[0]-mn) + __expf(sl[1]-mn)
                  + __expf(sl[2]-mn) + __expf(sl[3]-mn);
            m[ii] = mn;
        }
    }

    // combine row stats across the 16 tx-lanes (consecutive lanes, same ty)
    #pragma unroll
    for (int ii = 0; ii < 4; ++ii) {
        #pragma unroll
        for (int mk = 8; mk >= 1; mk >>= 1) {
            float mo = __shfl_xor(m[ii], mk);
            float lo = __shfl_xor(l[ii], mk);
            float mn = fmaxf(m[ii], mo);
            l[ii] = l[ii] * __expf(m[ii] - mn) + lo * __expf(mo - mn);
            m[ii] = mn;
        }
    }
    float inv_l[4];
    #pragma unroll
    for (int ii = 0; ii < 4; ++ii) inv_l[ii] = 1.0f / l[ii];

    // ---------- pass 2: write attn, accumulate z ----------
    float zacc[4][4] = {};
    for (int jt = 0; jt < 32; ++jt) {
        if (jt > it) {  // masked tile: attn = 0 exactly (uniform branch)
            float4 zz = make_float4(0.f, 0.f, 0.f, 0.f);
            #pragma unroll
            for (int ii = 0; ii < 4; ++ii)
                *(float4*)(Ah + (size_t)(i0 + ty*4 + ii) * 2048 + jt*64 + tx*4) = zz;
            continue;
        }
        __syncthreads();   // prior z-phase readers of kb/vb done
        #pragma unroll
        for (int q = 0; q < 4; ++q) {
            const int col = lc + q * 16;
            float4 t = *(const float4*)(Kh + (size_t)(jt*64 + lr) * 64 + col);
            kb[col+0][lr] = t.x; kb[col+1][lr] = t.y;
            kb[col+2][lr] = t.z; kb[col+3][lr] = t.w;
            float4 w = *(const float4*)(Vv + (size_t)(jt*64 + lr) * 64 + col);
            *(float4*)&vb[lr][col] = w;
        }
        __syncthreads();

        float s[4][4] = {};
        #pragma unroll 8
        for (int d = 0; d < 64; ++d) {
            float4 a = *(const float4*)&qs[d][ty*4];
            float4 b = *(const float4*)&kb[d][tx*4];
            float av[4] = {a.x, a.y, a.z, a.w};
            float bv[4] = {b.x, b.y, b.z, b.w};
            #pragma unroll
            for (int ii = 0; ii < 4; ++ii)
                #pragma unroll
                for (int jj = 0; jj < 4; ++jj)
                    s[ii][jj] += av[ii] * bv[jj];
        }
        const bool diag = (jt == it);
        float p[4][4];
        #pragma unroll
        for (int ii = 0; ii < 4; ++ii) {
            #pragma unroll
            for (int jj = 0; jj < 4; ++jj) {
                float lv = s[ii][jj] * 1000.0f;
                if (diag && (tx*4+jj > ty*4+ii)) lv = -1.0e9f;
                p[ii][jj] = __expf(lv - m[ii]) * inv_l[ii];
            }
            float4 pv = make_float4(p[ii][0], p[ii][1], p[ii][2], p[ii][3]);
            *(float4*)(Ah + (size_t)(i0 + ty*4 + ii) * 2048 + jt*64 + tx*4) = pv;
        }
        __syncthreads();   // all S-readers of kb done; reuse kb as ab[i][j]
        #pragma unroll
        for (int ii = 0; ii < 4; ++ii) {
            float4 pv = make_float4(p[ii][0], p[ii][1], p[ii][2], p[ii][3]);
            *(float4*)&kb[ty*4 + ii][tx*4] = pv;
        }
        __syncthreads();
        #pragma unroll 4
        for (int j = 0; j < 64; ++j) {
            float4 v4 = *(const float4*)&vb[j][tx*4];
            #pragma unroll
            for (int ii = 0; ii < 4; ++ii) {
                float aat = kb[ty*4 + ii][j];
                zacc[ii][0] += aat * v4.x;
                zacc[ii][1] += aat * v4.y;
                zacc[ii][2] += aat * v4.z;
                zacc[ii][3] += aat * v4.w;
            }
        }
    }

    #pragma unroll
    for (int ii = 0; ii < 4; ++ii) {
        float4 zv = make_float4(zacc[ii][0], zacc[ii][1], zacc[ii][2], zacc[ii][3]);
        *(float4*)(Z + (size_t)head * (2048*64) + (size_t)(i0 + ty*4 + ii) * 64 + tx*4) = zv;
    }
}

// ------------------------------------------------------------------
// K4: out0 = ZC @ Wz + bz.  ZC[R,c] lives in Z at
//   (R>>11)*2097152 + (R&2047)*64 + (c>>6)*131072 + (c&63)
// Out row-major (4096,1024).
// ------------------------------------------------------------------
__global__ __launch_bounds__(256) void out_gemm(
    const float* __restrict__ Z, const float* __restrict__ W,
    const float* __restrict__ bias, float* __restrict__ Out)
{
    __shared__ float As[16][65];
    __shared__ float Bs[16][68];
    const int tid = (int)threadIdx.x;
    const int tx = tid & 15;       // e-group (fast -> coalesced rm store)
    const int ty = tid >> 4;       // r-group
    const int r0 = blockIdx.y * 64;
    const int e0 = blockIdx.x * 64;

    const int lar = tid >> 2;
    const int lak = (tid & 3) * 4;
    const int lbk = tid >> 4;
    const int lbe = (tid & 15) * 4;

    float acc[4][4] = {};

    for (int k0 = 0; k0 < 1024; k0 += 16) {
        const int R = r0 + lar;
        const int c = k0 + lak;
        const float* ap = Z + ((size_t)(R >> 11) * 2097152)
                            + (size_t)(R & 2047) * 64
                            + (size_t)(c >> 6) * 131072 + (c & 63);
        float4 av = *(const float4*)ap;
        float4 bv = *(const float4*)(W + (size_t)(k0 + lbk) * 1024 + e0 + lbe);
        __syncthreads();
        As[lak+0][lar] = av.x; As[lak+1][lar] = av.y;
        As[lak+2][lar] = av.z; As[lak+3][lar] = av.w;
        Bs[lbk][lbe+0] = bv.x; Bs[lbk][lbe+1] = bv.y;
        Bs[lbk][lbe+2] = bv.z; Bs[lbk][lbe+3] = bv.w;
        __syncthreads();
        #pragma unroll
        for (int kk = 0; kk < 16; ++kk) {
            float a[4], b[4];
            #pragma unroll
            for (int i = 0; i < 4; ++i) a[i] = As[kk][ty*4+i];
            #pragma unroll
            for (int j = 0; j < 4; ++j) b[j] = Bs[kk][tx*4+j];
            #pragma unroll
            for (int i = 0; i < 4; ++i)
                #pragma unroll
                for (int j = 0; j < 4; ++j)
                    acc[i][j] += a[i] * b[j];
        }
    }
    #pragma unroll
    for (int i = 0; i < 4; ++i) {
        float4 v;
        v.x = acc[i][0] + bias[e0 + tx*4 + 0];
        v.y = acc[i][1] + bias[e0 + tx*4 + 1];
        v.z = acc[i][2] + bias[e0 + tx*4 + 2];
        v.w = acc[i][3] + bias[e0 + tx*4 + 3];
        *(float4*)(Out + (size_t)(r0 + ty*4 + i) * 1024 + e0 + tx*4) = v;
    }
}

// ------------------------------------------------------------------
extern "C" void kernel_launch(void* const* d_in, const int* in_sizes, int n_in,
                              void* d_out, int out_size, void* d_ws, size_t ws_size,
                              hipStream_t stream) {
    (void)in_sizes; (void)n_in; (void)out_size;
    const float* q  = (const float*)d_in[0];
    const float* k  = (const float*)d_in[1];
    const float* v  = (const float*)d_in[2];
    // d_in[3] = mask (causal, reproduced analytically)
    const float* Wq = (const float*)d_in[4];  const float* bq = (const float*)d_in[5];
    const float* Wk = (const float*)d_in[6];  const float* bk = (const float*)d_in[7];
    const float* Wv = (const float*)d_in[8];  const float* bv = (const float*)d_in[9];
    const float* Wz = (const float*)d_in[10]; const float* bz = (const float*)d_in[11];

    float* out0 = (float*)d_out;              // (2,2048,1024) = 4194304 floats
    float* attn = out0 + 4194304;             // (2,16,2048,2048) = 134217728 floats

    // Stage PT scratch inside the (not yet written) attn output region: 48 MB.
    float* PTq = attn;
    float* PTk = attn + 4194304;
    float* PTv = attn + 8388608;

    // qn/kn/vh/z: 64 MB. Prefer d_ws; fall back to clobbering consumed inputs
    // (harness restores d_in from pristine copies before every launch).
    float *Qn, *Kn, *Vhd, *Z;
    float* ws = (float*)d_ws;
    if (ws_size >= (size_t)67108864) {
        Qn = ws; Kn = ws + 4194304; Vhd = ws + 8388608; Z = ws + 12582912;
    } else {
        Qn = (float*)d_in[0]; Kn = (float*)d_in[1]; Vhd = (float*)d_in[2]; Z = ws;
    }

    dim3 ggrid(16, 64);
    proj_gemm_t<<<ggrid, 256, 0, stream>>>(q, Wq, bq, PTq);
    proj_gemm_t<<<ggrid, 256, 0, stream>>>(k, Wk, bk, PTk);
    proj_gemm_t<<<ggrid, 256, 0, stream>>>(v, Wv, bv, PTv);

    gather_heads<<<16384, 256, 0, stream>>>(PTq, Qn, 1);
    gather_heads<<<16384, 256, 0, stream>>>(PTk, Kn, 1);
    gather_heads<<<16384, 256, 0, stream>>>(PTv, Vhd, 0);

    attn_kernel<<<dim3(32, 32), 256, 0, stream>>>(Qn, Kn, Vhd, attn, Z);

    out_gemm<<<dim3(16, 64), 256, 0, stream>>>(Z, Wz, bz, out0);
}

// Round 2
// 1478.368 us; speedup vs baseline: 1.1554x; 1.1554x over previous
//
#include <hip/hip_runtime.h>
#include <cstdint>
#include <cstddef>

// B=2, S=2048, E=1024, H=16, HD=64; rows = 4096; heads = 32.
//
// All GEMMs use bf16 hi/lo split-MFMA: x = hi + lo (each bf16) represents x to
// ~2^-18 rel. C = Ahi Bhi + Alo Bhi + Ahi Blo + Alo Blo, fp32 MFMA accum.
// A stored as Ap[m][2048] = [hi(row) | lo(row)] (k contiguous).
// B stored transposed Bp[n][2048] = [hi(col) | lo(col)] (k contiguous) so both
// operands stage/ds_read identically (m92 "B^T input" trick).

typedef __bf16 bf16x4 __attribute__((ext_vector_type(4)));
typedef __bf16 bf16x8 __attribute__((ext_vector_type(8)));
typedef float floatx4 __attribute__((ext_vector_type(4)));

#define GLOAD_LDS16(g, l)                                                      \
    __builtin_amdgcn_global_load_lds(                                          \
        (const __attribute__((address_space(1))) void*)(g),                    \
        (__attribute__((address_space(3))) void*)(l), 16, 0, 0)

// ------------------------------------------------------------------
// split_a: X fp32 (4096x1024, rm) -> Ap bf16 (4096x2048): [hi | lo] per row.
// grid (4096,1,3): z selects q/k/v; Ap stride 4096*2048.
// ------------------------------------------------------------------
__global__ __launch_bounds__(256) void split_a(
    const float* __restrict__ x0, const float* __restrict__ x1,
    const float* __restrict__ x2, __bf16* __restrict__ ApBase)
{
    const float* X = blockIdx.z == 0 ? x0 : (blockIdx.z == 1 ? x1 : x2);
    __bf16* Ap = ApBase + (size_t)blockIdx.z * (4096ull * 2048);
    const int idx = blockIdx.x * 256 + threadIdx.x;   // 0..1048575
    const int r = idx >> 8;
    const int c = (idx & 255) * 4;
    float4 t = *(const float4*)(X + (size_t)r * 1024 + c);
    bf16x4 hi, lo;
    hi[0] = (__bf16)t.x; lo[0] = (__bf16)(t.x - (float)hi[0]);
    hi[1] = (__bf16)t.y; lo[1] = (__bf16)(t.y - (float)hi[1]);
    hi[2] = (__bf16)t.z; lo[2] = (__bf16)(t.z - (float)hi[2]);
    hi[3] = (__bf16)t.w; lo[3] = (__bf16)(t.w - (float)hi[3]);
    *(bf16x4*)(Ap + (size_t)r * 2048 + c) = hi;
    *(bf16x4*)(Ap + (size_t)r * 2048 + 1024 + c) = lo;
}

// ------------------------------------------------------------------
// split_bt: W fp32 (1024x1024 rm, [k][n]) -> Bp bf16 (1024x2048): row n holds
// [hi(W[:,n]) | lo(W[:,n])] (k contiguous). grid (16,16,z).
// ------------------------------------------------------------------
__global__ __launch_bounds__(256) void split_bt(
    const float* __restrict__ w0, const float* __restrict__ w1,
    const float* __restrict__ w2, __bf16* __restrict__ dstBase, size_t dstStride)
{
    const float* W = blockIdx.z == 0 ? w0 : (blockIdx.z == 1 ? w1 : w2);
    __bf16* Bp = dstBase + (size_t)blockIdx.z * dstStride;
    __shared__ float tile[64][65];
    const int tid = (int)threadIdx.x;
    const int k0 = blockIdx.y * 64, n0 = blockIdx.x * 64;
    #pragma unroll
    for (int p = 0; p < 4; ++p) {
        int kr = p * 16 + (tid >> 4);
        float4 t = *(const float4*)(W + (size_t)(k0 + kr) * 1024 + n0 + (tid & 15) * 4);
        tile[kr][(tid & 15) * 4 + 0] = t.x; tile[kr][(tid & 15) * 4 + 1] = t.y;
        tile[kr][(tid & 15) * 4 + 2] = t.z; tile[kr][(tid & 15) * 4 + 3] = t.w;
    }
    __syncthreads();
    const int nr = tid >> 2, kc = (tid & 3) * 16;
    bf16x8 hi0, hi1, lo0, lo1;
    #pragma unroll
    for (int j = 0; j < 8; ++j) {
        float x = tile[kc + j][nr];
        __bf16 h = (__bf16)x; hi0[j] = h; lo0[j] = (__bf16)(x - (float)h);
        float y = tile[kc + 8 + j][nr];
        __bf16 g = (__bf16)y; hi1[j] = g; lo1[j] = (__bf16)(y - (float)g);
    }
    __bf16* row = Bp + (size_t)(n0 + nr) * 2048;
    *(bf16x8*)(row + k0 + kc)          = hi0;
    *(bf16x8*)(row + k0 + kc + 8)      = hi1;
    *(bf16x8*)(row + 1024 + k0 + kc)     = lo0;
    *(bf16x8*)(row + 1024 + k0 + kc + 8) = lo1;
}

// ------------------------------------------------------------------
// gemm_split: C(4096x1024) = A * B (+bias), 4 hi/lo chunks, MFMA 16x16x32 bf16.
// 128x128 tile, BK=32, 4 waves (2x2), each wave 64x64 (4x4 MFMA tiles).
// transposeOut=1: store PT[e][r] (row len 4096). else row-major [r][e].
// grid (8, 32, z). Ap stride 4096*2048; Bp stride 1024*2048; Out stride 4096*1024.
// ------------------------------------------------------------------
__global__ __launch_bounds__(256) void gemm_split(
    const __bf16* __restrict__ Ap0, const __bf16* __restrict__ Bp0,
    const float* __restrict__ b0, const float* __restrict__ b1,
    const float* __restrict__ b2, float* __restrict__ Out0,
    int transposeOut)
{
    const int z = blockIdx.z;
    const __bf16* Ap = Ap0 + (size_t)z * (4096ull * 2048);
    const __bf16* Bp = Bp0 + (size_t)z * (1024ull * 2048);
    const float* bias = z == 0 ? b0 : (z == 1 ? b1 : b2);
    float* Out = Out0 + (size_t)z * (4096ull * 1024);

    __shared__ __bf16 As[128 * 32];   // [row][k] rows of 64B
    __shared__ __bf16 Bs[128 * 32];

    const int tid = (int)threadIdx.x;
    const int wave = tid >> 6, lane = tid & 63;
    const int quad = lane >> 4, tl = lane & 15;
    const int m0 = blockIdx.y * 128, n0 = blockIdx.x * 128;
    const int waveM = wave >> 1, waveN = wave & 1;

    floatx4 acc[4][4];
    #pragma unroll
    for (int i = 0; i < 4; ++i)
        #pragma unroll
        for (int j = 0; j < 4; ++j)
            acc[i][j] = (floatx4){0.f, 0.f, 0.f, 0.f};

    // staging: each lane loads 16B; 4 lanes per 64B (32-bf16) row chunk
    const int sRow  = (wave << 4) + (lane >> 2);   // + i*64
    const int sColB = (lane & 3) << 4;             // byte offset within chunk
    auto* AsL = (__attribute__((address_space(3))) char*)As;
    auto* BsL = (__attribute__((address_space(3))) char*)Bs;
    const int ldsOff = wave * 1024;                // wave-uniform

    const int aOffs[4] = {0, 1024, 0, 1024};
    const int bOffs[4] = {0, 0, 1024, 1024};

    for (int ch = 0; ch < 4; ++ch) {
        const __bf16* Ach = Ap + aOffs[ch];
        const __bf16* Bch = Bp + bOffs[ch];
        for (int k0 = 0; k0 < 1024; k0 += 32) {
            __syncthreads();   // prior frag reads done before overwrite
            #pragma unroll
            for (int i = 0; i < 2; ++i) {
                GLOAD_LDS16(
                    (const char*)(Ach + (size_t)(m0 + i * 64 + sRow) * 2048 + k0) + sColB,
                    AsL + i * 4096 + ldsOff);
                GLOAD_LDS16(
                    (const char*)(Bch + (size_t)(n0 + i * 64 + sRow) * 2048 + k0) + sColB,
                    BsL + i * 4096 + ldsOff);
            }
            __syncthreads();   // drains vmcnt -> LDS valid

            bf16x8 af[4], bfr[4];
            #pragma unroll
            for (int mt = 0; mt < 4; ++mt)
                af[mt] = *(const bf16x8*)(As + (waveM * 64 + mt * 16 + tl) * 32 + quad * 8);
            #pragma unroll
            for (int nt = 0; nt < 4; ++nt)
                bfr[nt] = *(const bf16x8*)(Bs + (waveN * 64 + nt * 16 + tl) * 32 + quad * 8);
            #pragma unroll
            for (int mt = 0; mt < 4; ++mt)
                #pragma unroll
                for (int nt = 0; nt < 4; ++nt)
                    acc[mt][nt] = __builtin_amdgcn_mfma_f32_16x16x32_bf16(
                        af[mt], bfr[nt], acc[mt][nt], 0, 0, 0);
        }
    }

    // C/D layout: row = quad*4 + reg (m), col = tl (n)
    if (transposeOut) {
        #pragma unroll
        for (int nt = 0; nt < 4; ++nt) {
            const int e = n0 + waveN * 64 + nt * 16 + tl;
            const float bb = bias[e];
            #pragma unroll
            for (int mt = 0; mt < 4; ++mt) {
                floatx4 v = acc[mt][nt] + bb;   // regs = 4 consecutive m
                *(floatx4*)(Out + (size_t)e * 4096 + m0 + waveM * 64 + mt * 16 + quad * 4) = v;
            }
        }
    } else {
        #pragma unroll
        for (int mt = 0; mt < 4; ++mt) {
            const int rbase = m0 + waveM * 64 + mt * 16 + quad * 4;
            #pragma unroll
            for (int nt = 0; nt < 4; ++nt) {
                const int e = n0 + waveN * 64 + nt * 16 + tl;
                const float bb = bias[e];
                #pragma unroll
                for (int reg = 0; reg < 4; ++reg)
                    Out[(size_t)(rbase + reg) * 1024 + e] = acc[mt][nt][reg] + bb;
            }
        }
    }
}

// ------------------------------------------------------------------
// gather scrambled heads from PT[e][r], optional L2-normalize.
// qh[b',h,s',d] = P[(d&1)*2048+(s'&63)*32+(d>>1)][b'*512+h*32+(s'>>6)]
// ------------------------------------------------------------------
__global__ __launch_bounds__(256) void gather_heads(
    const float* __restrict__ PT, float* __restrict__ Out, int do_norm)
{
    const int tid  = (int)threadIdx.x;
    const int lane = tid & 63;
    const int vec  = blockIdx.x * 4 + (tid >> 6);
    const int head = vec >> 11;
    const int sp   = vec & 2047;
    const int c    = (head >> 4) * 512 + (head & 15) * 32 + (sp >> 6);
    const int src  = (lane & 1) * 2048 + (sp & 63) * 32 + (lane >> 1);
    float v = PT[(size_t)c * 4096 + src];
    if (do_norm) {
        float ss = v * v;
        #pragma unroll
        for (int mk = 32; mk >= 1; mk >>= 1) ss += __shfl_xor(ss, mk);
        v = v / sqrtf(ss);
    }
    Out[(size_t)vec * 64 + lane] = v;
}

// ------------------------------------------------------------------
// attention (fp32 VALU, unchanged except z is stored as bf16 hi/lo in
// A-operand layout for the final split-GEMM): Az[R][2048], R=b*2048+s,
// cols [h*64+d] = hi, [1024+h*64+d] = lo.
// ------------------------------------------------------------------
__global__ __launch_bounds__(256) void attn_kernel(
    const float* __restrict__ Qn, const float* __restrict__ Kn,
    const float* __restrict__ Vh, float* __restrict__ Attn,
    __bf16* __restrict__ Az)
{
    const int it   = blockIdx.x;
    const int head = blockIdx.y;
    const int tid  = (int)threadIdx.x;
    const int tx = tid & 15;
    const int ty = tid >> 4;
    const int i0 = it * 64;

    const float* __restrict__ Qh = Qn + (size_t)head * (2048*64);
    const float* __restrict__ Kh = Kn + (size_t)head * (2048*64);
    const float* __restrict__ Vv = Vh + (size_t)head * (2048*64);
    float* __restrict__ Ah = Attn + (size_t)head * ((size_t)2048*2048);

    __shared__ float qs[64][68];
    __shared__ float kb[64][68];
    __shared__ float vb[64][68];

    const int lr = tid >> 2;
    const int lc = (tid & 3) * 4;

    #pragma unroll
    for (int q = 0; q < 4; ++q) {
        const int col = lc + q * 16;
        float4 t = *(const float4*)(Qh + (size_t)(i0 + lr) * 64 + col);
        qs[col+0][lr] = t.x; qs[col+1][lr] = t.y;
        qs[col+2][lr] = t.z; qs[col+3][lr] = t.w;
    }

    float m[4], l[4];
    #pragma unroll
    for (int i = 0; i < 4; ++i) { m[i] = -3.0e38f; l[i] = 0.0f; }

    for (int jt = 0; jt <= it; ++jt) {
        __syncthreads();
        #pragma unroll
        for (int q = 0; q < 4; ++q) {
            const int col = lc + q * 16;
            float4 t = *(const float4*)(Kh + (size_t)(jt*64 + lr) * 64 + col);
            kb[col+0][lr] = t.x; kb[col+1][lr] = t.y;
            kb[col+2][lr] = t.z; kb[col+3][lr] = t.w;
        }
        __syncthreads();

        float s[4][4] = {};
        #pragma unroll 8
        for (int d = 0; d < 64; ++d) {
            float4 a = *(const float4*)&qs[d][ty*4];
            float4 b = *(const float4*)&kb[d][tx*4];
            float av[4] = {a.x, a.y, a.z, a.w};
            float bv[4] = {b.x, b.y, b.z, b.w};
            #pragma unroll
            for (int ii = 0; ii < 4; ++ii)
                #pragma unroll
                for (int jj = 0; jj < 4; ++jj)
                    s[ii][jj] += av[ii] * bv[jj];
        }
        const bool diag = (jt == it);
        #pragma unroll
        for (int ii = 0; ii < 4; ++ii) {
            float sl[4];
            #pragma unroll
            for (int jj = 0; jj < 4; ++jj) {
                float lv = s[ii][jj] * 1000.0f;
                if (diag && (tx*4+jj > ty*4+ii)) lv = -1.0e9f;
                sl[jj] = lv;
            }
            float mt = fmaxf(fmaxf(sl[0], sl[1]), fmaxf(sl[2], sl[3]));
            float mn = fmaxf(m[ii], mt);
            l[ii] = l[ii] * __expf(m[ii] - mn)
                  + __expf(sl[0]-mn) + __expf(sl[1]-mn)
                  + __expf(sl[2]-mn) + __expf(sl[3]-mn);
            m[ii] = mn;
        }
    }

    #pragma unroll
    for (int ii = 0; ii < 4; ++ii) {
        #pragma unroll
        for (int mk = 8; mk >= 1; mk >>= 1) {
            float mo = __shfl_xor(m[ii], mk);
            float lo = __shfl_xor(l[ii], mk);
            float mn = fmaxf(m[ii], mo);
            l[ii] = l[ii] * __expf(m[ii] - mn) + lo * __expf(mo - mn);
            m[ii] = mn;
        }
    }
    float inv_l[4];
    #pragma unroll
    for (int ii = 0; ii < 4; ++ii) inv_l[ii] = 1.0f / l[ii];

    float zacc[4][4] = {};
    for (int jt = 0; jt < 32; ++jt) {
        if (jt > it) {
            float4 zz = make_float4(0.f, 0.f, 0.f, 0.f);
            #pragma unroll
            for (int ii = 0; ii < 4; ++ii)
                *(float4*)(Ah + (size_t)(i0 + ty*4 + ii) * 2048 + jt*64 + tx*4) = zz;
            continue;
        }
        __syncthreads();
        #pragma unroll
        for (int q = 0; q < 4; ++q) {
            const int col = lc + q * 16;
            float4 t = *(const float4*)(Kh + (size_t)(jt*64 + lr) * 64 + col);
            kb[col+0][lr] = t.x; kb[col+1][lr] = t.y;
            kb[col+2][lr] = t.z; kb[col+3][lr] = t.w;
            float4 w = *(const float4*)(Vv + (size_t)(jt*64 + lr) * 64 + col);
            *(float4*)&vb[lr][col] = w;
        }
        __syncthreads();

        float s[4][4] = {};
        #pragma unroll 8
        for (int d = 0; d < 64; ++d) {
            float4 a = *(const float4*)&qs[d][ty*4];
            float4 b = *(const float4*)&kb[d][tx*4];
            float av[4] = {a.x, a.y, a.z, a.w};
            float bv[4] = {b.x, b.y, b.z, b.w};
            #pragma unroll
            for (int ii = 0; ii < 4; ++ii)
                #pragma unroll
                for (int jj = 0; jj < 4; ++jj)
                    s[ii][jj] += av[ii] * bv[jj];
        }
        const bool diag = (jt == it);
        float p[4][4];
        #pragma unroll
        for (int ii = 0; ii < 4; ++ii) {
            #pragma unroll
            for (int jj = 0; jj < 4; ++jj) {
                float lv = s[ii][jj] * 1000.0f;
                if (diag && (tx*4+jj > ty*4+ii)) lv = -1.0e9f;
                p[ii][jj] = __expf(lv - m[ii]) * inv_l[ii];
            }
            float4 pv = make_float4(p[ii][0], p[ii][1], p[ii][2], p[ii][3]);
            *(float4*)(Ah + (size_t)(i0 + ty*4 + ii) * 2048 + jt*64 + tx*4) = pv;
        }
        __syncthreads();
        #pragma unroll
        for (int ii = 0; ii < 4; ++ii) {
            float4 pv = make_float4(p[ii][0], p[ii][1], p[ii][2], p[ii][3]);
            *(float4*)&kb[ty*4 + ii][tx*4] = pv;
        }
        __syncthreads();
        #pragma unroll 4
        for (int j = 0; j < 64; ++j) {
            float4 v4 = *(const float4*)&vb[j][tx*4];
            #pragma unroll
            for (int ii = 0; ii < 4; ++ii) {
                float aat = kb[ty*4 + ii][j];
                zacc[ii][0] += aat * v4.x;
                zacc[ii][1] += aat * v4.y;
                zacc[ii][2] += aat * v4.z;
                zacc[ii][3] += aat * v4.w;
            }
        }
    }

    // z -> Az bf16 hi/lo (A-layout for out-GEMM): R = b*2048+s, col = h*64+d
    const int b  = head >> 4, h = head & 15;
    #pragma unroll
    for (int ii = 0; ii < 4; ++ii) {
        const size_t R = (size_t)b * 2048 + i0 + ty*4 + ii;
        bf16x4 hi, lo;
        #pragma unroll
        for (int jj = 0; jj < 4; ++jj) {
            float x = zacc[ii][jj];
            __bf16 hh = (__bf16)x;
            hi[jj] = hh; lo[jj] = (__bf16)(x - (float)hh);
        }
        *(bf16x4*)(Az + R * 2048 + h*64 + tx*4) = hi;
        *(bf16x4*)(Az + R * 2048 + 1024 + h*64 + tx*4) = lo;
    }
}

// ------------------------------------------------------------------
extern "C" void kernel_launch(void* const* d_in, const int* in_sizes, int n_in,
                              void* d_out, int out_size, void* d_ws, size_t ws_size,
                              hipStream_t stream) {
    (void)in_sizes; (void)n_in; (void)out_size;
    const float* q  = (const float*)d_in[0];
    const float* k  = (const float*)d_in[1];
    const float* v  = (const float*)d_in[2];
    const float* Wq = (const float*)d_in[4];  const float* bq = (const float*)d_in[5];
    const float* Wk = (const float*)d_in[6];  const float* bk = (const float*)d_in[7];
    const float* Wv = (const float*)d_in[8];  const float* bv = (const float*)d_in[9];
    const float* Wz = (const float*)d_in[10]; const float* bz = (const float*)d_in[11];

    float* out0 = (float*)d_out;               // (2,2048,1024)
    float* attn = out0 + 4194304;              // (2,16,2048,2048) = 512 MB

    // Scratch inside the not-yet-written attn region (134M floats):
    float*  PT0 = attn;                                   // 3 x 4M floats (PT[e][r])
    __bf16* Ap0 = (__bf16*)(attn + 12582912);             // 3 x 4096x2048 bf16
    __bf16* Bp0 = (__bf16*)(attn + 12582912 + 12582912);  // 3 x 1024x2048 bf16

    // Bpz (Wz split, needed after attn overwrites the region): reuse Wq's
    // buffer (4 MB, consumed by split_bt before this is written).
    __bf16* Bpz = (__bf16*)d_in[4];

    // Qn/Kn/Vh fp32 + Az bf16 (4096x2048): prefer ws (64 MB), else clobber
    // consumed inputs (harness restores d_in before every launch).
    float *Qn, *Kn, *Vhd; __bf16* Az;
    float* ws = (float*)d_ws;
    if (ws_size >= (size_t)67108864) {
        Qn = ws; Kn = ws + 4194304; Vhd = ws + 8388608;
        Az = (__bf16*)(ws + 12582912);
    } else {
        Qn = (float*)d_in[0]; Kn = (float*)d_in[1]; Vhd = (float*)d_in[2];
        Az = (__bf16*)ws;
    }

    split_a <<<dim3(4096, 1, 3), 256, 0, stream>>>(q, k, v, Ap0);
    split_bt<<<dim3(16, 16, 3), 256, 0, stream>>>(Wq, Wk, Wv, Bp0, 1024ull*2048);

    gemm_split<<<dim3(8, 32, 3), 256, 0, stream>>>(Ap0, Bp0, bq, bk, bv, PT0, 1);

    gather_heads<<<16384, 256, 0, stream>>>(PT0,            Qn,  1);
    gather_heads<<<16384, 256, 0, stream>>>(PT0 + 4194304,  Kn,  1);
    gather_heads<<<16384, 256, 0, stream>>>(PT0 + 8388608,  Vhd, 0);

    split_bt<<<dim3(16, 16, 1), 256, 0, stream>>>(Wz, Wz, Wz, Bpz, 0);

    attn_kernel<<<dim3(32, 32), 256, 0, stream>>>(Qn, Kn, Vhd, attn, Az);

    gemm_split<<<dim3(8, 32, 1), 256, 0, stream>>>(Az, Bpz, bz, bz, bz, out0, 0);
}

// Round 3
// 1080.344 us; speedup vs baseline: 1.5811x; 1.3684x over previous
//
#include <hip/hip_runtime.h>
#include <cstdint>
#include <cstddef>

// B=2, S=2048, E=1024, H=16, HD=64; rows = 4096; heads = 32.
//
// All GEMMs use bf16 hi/lo split-MFMA (validated r2: absmax unchanged vs fp32).
// Attention (this round) also MFMA: QK^T = Qhi Khi + Qhi Klo + Qlo Khi (lo*lo
// dropped, <=0.004 logit err), PV = P_bf16 * (Vhi + Vlo).

typedef __bf16 bf16x4 __attribute__((ext_vector_type(4)));
typedef __bf16 bf16x8 __attribute__((ext_vector_type(8)));
typedef float floatx4 __attribute__((ext_vector_type(4)));

#define GLOAD_LDS16(g, l)                                                      \
    __builtin_amdgcn_global_load_lds(                                          \
        (const __attribute__((address_space(1))) void*)(g),                    \
        (__attribute__((address_space(3))) void*)(l), 16, 0, 0)

// ------------------------------------------------------------------
// split_a: X fp32 (4096x1024, rm) -> Ap bf16 (4096x2048): [hi | lo] per row.
// ------------------------------------------------------------------
__global__ __launch_bounds__(256) void split_a(
    const float* __restrict__ x0, const float* __restrict__ x1,
    const float* __restrict__ x2, __bf16* __restrict__ ApBase)
{
    const float* X = blockIdx.z == 0 ? x0 : (blockIdx.z == 1 ? x1 : x2);
    __bf16* Ap = ApBase + (size_t)blockIdx.z * (4096ull * 2048);
    const int idx = blockIdx.x * 256 + threadIdx.x;
    const int r = idx >> 8;
    const int c = (idx & 255) * 4;
    float4 t = *(const float4*)(X + (size_t)r * 1024 + c);
    bf16x4 hi, lo;
    hi[0] = (__bf16)t.x; lo[0] = (__bf16)(t.x - (float)hi[0]);
    hi[1] = (__bf16)t.y; lo[1] = (__bf16)(t.y - (float)hi[1]);
    hi[2] = (__bf16)t.z; lo[2] = (__bf16)(t.z - (float)hi[2]);
    hi[3] = (__bf16)t.w; lo[3] = (__bf16)(t.w - (float)hi[3]);
    *(bf16x4*)(Ap + (size_t)r * 2048 + c) = hi;
    *(bf16x4*)(Ap + (size_t)r * 2048 + 1024 + c) = lo;
}

// ------------------------------------------------------------------
// split_bt: W fp32 (1024x1024 rm, [k][n]) -> Bp bf16 (1024x2048): row n holds
// [hi(W[:,n]) | lo(W[:,n])].
// ------------------------------------------------------------------
__global__ __launch_bounds__(256) void split_bt(
    const float* __restrict__ w0, const float* __restrict__ w1,
    const float* __restrict__ w2, __bf16* __restrict__ dstBase, size_t dstStride)
{
    const float* W = blockIdx.z == 0 ? w0 : (blockIdx.z == 1 ? w1 : w2);
    __bf16* Bp = dstBase + (size_t)blockIdx.z * dstStride;
    __shared__ float tile[64][65];
    const int tid = (int)threadIdx.x;
    const int k0 = blockIdx.y * 64, n0 = blockIdx.x * 64;
    #pragma unroll
    for (int p = 0; p < 4; ++p) {
        int kr = p * 16 + (tid >> 4);
        float4 t = *(const float4*)(W + (size_t)(k0 + kr) * 1024 + n0 + (tid & 15) * 4);
        tile[kr][(tid & 15) * 4 + 0] = t.x; tile[kr][(tid & 15) * 4 + 1] = t.y;
        tile[kr][(tid & 15) * 4 + 2] = t.z; tile[kr][(tid & 15) * 4 + 3] = t.w;
    }
    __syncthreads();
    const int nr = tid >> 2, kc = (tid & 3) * 16;
    bf16x8 hi0, hi1, lo0, lo1;
    #pragma unroll
    for (int j = 0; j < 8; ++j) {
        float x = tile[kc + j][nr];
        __bf16 h = (__bf16)x; hi0[j] = h; lo0[j] = (__bf16)(x - (float)h);
        float y = tile[kc + 8 + j][nr];
        __bf16 g = (__bf16)y; hi1[j] = g; lo1[j] = (__bf16)(y - (float)g);
    }
    __bf16* row = Bp + (size_t)(n0 + nr) * 2048;
    *(bf16x8*)(row + k0 + kc)          = hi0;
    *(bf16x8*)(row + k0 + kc + 8)      = hi1;
    *(bf16x8*)(row + 1024 + k0 + kc)     = lo0;
    *(bf16x8*)(row + 1024 + k0 + kc + 8) = lo1;
}

// ------------------------------------------------------------------
// gemm_split: C(4096x1024) = A*B (+bias), 4 hi/lo chunks, MFMA 16x16x32 bf16.
// (unchanged from r2 — validated)
// ------------------------------------------------------------------
__global__ __launch_bounds__(256) void gemm_split(
    const __bf16* __restrict__ Ap0, const __bf16* __restrict__ Bp0,
    const float* __restrict__ b0, const float* __restrict__ b1,
    const float* __restrict__ b2, float* __restrict__ Out0,
    int transposeOut)
{
    const int z = blockIdx.z;
    const __bf16* Ap = Ap0 + (size_t)z * (4096ull * 2048);
    const __bf16* Bp = Bp0 + (size_t)z * (1024ull * 2048);
    const float* bias = z == 0 ? b0 : (z == 1 ? b1 : b2);
    float* Out = Out0 + (size_t)z * (4096ull * 1024);

    __shared__ __bf16 As[128 * 32];
    __shared__ __bf16 Bs[128 * 32];

    const int tid = (int)threadIdx.x;
    const int wave = tid >> 6, lane = tid & 63;
    const int quad = lane >> 4, tl = lane & 15;
    const int m0 = blockIdx.y * 128, n0 = blockIdx.x * 128;
    const int waveM = wave >> 1, waveN = wave & 1;

    floatx4 acc[4][4];
    #pragma unroll
    for (int i = 0; i < 4; ++i)
        #pragma unroll
        for (int j = 0; j < 4; ++j)
            acc[i][j] = (floatx4){0.f, 0.f, 0.f, 0.f};

    const int sRow  = (wave << 4) + (lane >> 2);
    const int sColB = (lane & 3) << 4;
    auto* AsL = (__attribute__((address_space(3))) char*)As;
    auto* BsL = (__attribute__((address_space(3))) char*)Bs;
    const int ldsOff = wave * 1024;

    const int aOffs[4] = {0, 1024, 0, 1024};
    const int bOffs[4] = {0, 0, 1024, 1024};

    for (int ch = 0; ch < 4; ++ch) {
        const __bf16* Ach = Ap + aOffs[ch];
        const __bf16* Bch = Bp + bOffs[ch];
        for (int k0 = 0; k0 < 1024; k0 += 32) {
            __syncthreads();
            #pragma unroll
            for (int i = 0; i < 2; ++i) {
                GLOAD_LDS16(
                    (const char*)(Ach + (size_t)(m0 + i * 64 + sRow) * 2048 + k0) + sColB,
                    AsL + i * 4096 + ldsOff);
                GLOAD_LDS16(
                    (const char*)(Bch + (size_t)(n0 + i * 64 + sRow) * 2048 + k0) + sColB,
                    BsL + i * 4096 + ldsOff);
            }
            __syncthreads();

            bf16x8 af[4], bfr[4];
            #pragma unroll
            for (int mt = 0; mt < 4; ++mt)
                af[mt] = *(const bf16x8*)(As + (waveM * 64 + mt * 16 + tl) * 32 + quad * 8);
            #pragma unroll
            for (int nt = 0; nt < 4; ++nt)
                bfr[nt] = *(const bf16x8*)(Bs + (waveN * 64 + nt * 16 + tl) * 32 + quad * 8);
            #pragma unroll
            for (int mt = 0; mt < 4; ++mt)
                #pragma unroll
                for (int nt = 0; nt < 4; ++nt)
                    acc[mt][nt] = __builtin_amdgcn_mfma_f32_16x16x32_bf16(
                        af[mt], bfr[nt], acc[mt][nt], 0, 0, 0);
        }
    }

    if (transposeOut) {
        #pragma unroll
        for (int nt = 0; nt < 4; ++nt) {
            const int e = n0 + waveN * 64 + nt * 16 + tl;
            const float bb = bias[e];
            #pragma unroll
            for (int mt = 0; mt < 4; ++mt) {
                floatx4 v = acc[mt][nt] + bb;
                *(floatx4*)(Out + (size_t)e * 4096 + m0 + waveM * 64 + mt * 16 + quad * 4) = v;
            }
        }
    } else {
        #pragma unroll
        for (int mt = 0; mt < 4; ++mt) {
            const int rbase = m0 + waveM * 64 + mt * 16 + quad * 4;
            #pragma unroll
            for (int nt = 0; nt < 4; ++nt) {
                const int e = n0 + waveN * 64 + nt * 16 + tl;
                const float bb = bias[e];
                #pragma unroll
                for (int reg = 0; reg < 4; ++reg)
                    Out[(size_t)(rbase + reg) * 1024 + e] = acc[mt][nt][reg] + bb;
            }
        }
    }
}

// ------------------------------------------------------------------
// gather_qk: PT[e][4096] -> normalized head vectors, bf16 hi/lo.
// Outp[vec][128] = [hi(0..63) | lo(0..63)], vec = head*2048 + s'.
// ------------------------------------------------------------------
__global__ __launch_bounds__(256) void gather_qk(
    const float* __restrict__ PT, __bf16* __restrict__ Outp)
{
    const int tid  = (int)threadIdx.x;
    const int lane = tid & 63;
    const int vec  = blockIdx.x * 4 + (tid >> 6);
    const int head = vec >> 11;
    const int sp   = vec & 2047;
    const int c    = (head >> 4) * 512 + (head & 15) * 32 + (sp >> 6);
    const int src  = (lane & 1) * 2048 + (sp & 63) * 32 + (lane >> 1);
    float v = PT[(size_t)c * 4096 + src];
    float ss = v * v;
    #pragma unroll
    for (int mk = 32; mk >= 1; mk >>= 1) ss += __shfl_xor(ss, mk);
    v = v / sqrtf(ss);
    __bf16 h = (__bf16)v;
    Outp[(size_t)vec * 128 + lane]      = h;
    Outp[(size_t)vec * 128 + 64 + lane] = (__bf16)(v - (float)h);
}

// ------------------------------------------------------------------
// v_transpose: PTv[e][4096] -> Vt[head][d2=128][2048] bf16, d2 = d (hi) or
// 64+d (lo). One block per (64-s' tile, head); c is block-uniform.
// ------------------------------------------------------------------
__global__ __launch_bounds__(256) void v_transpose(
    const float* __restrict__ PTv, __bf16* __restrict__ Vt)
{
    const int head = blockIdx.y, st = blockIdx.x;
    const int tid = (int)threadIdx.x;
    const int c = (head >> 4) * 512 + (head & 15) * 32 + st;
    const float* __restrict__ row = PTv + (size_t)c * 4096;

    __shared__ float tile[64][65];   // [s'loc][d]
    #pragma unroll
    for (int i = 0; i < 4; ++i) {
        int o = i * 1024 + tid * 4;
        float4 t = *(const float4*)(row + o);
        float vals[4] = {t.x, t.y, t.z, t.w};
        #pragma unroll
        for (int e = 0; e < 4; ++e) {
            int oo = o + e;
            int d  = ((oo & 2047) & 31) * 2 + (oo >> 11);
            int sl = (oo & 2047) >> 5;
            tile[sl][d] = vals[e];
        }
    }
    __syncthreads();

    const int d = tid >> 2, jb = (tid & 3) * 16;
    bf16x8 h0, h1, l0, l1;
    #pragma unroll
    for (int j = 0; j < 8; ++j) {
        float x = tile[jb + j][d];
        __bf16 hh = (__bf16)x; h0[j] = hh; l0[j] = (__bf16)(x - (float)hh);
        float y = tile[jb + 8 + j][d];
        __bf16 gg = (__bf16)y; h1[j] = gg; l1[j] = (__bf16)(y - (float)gg);
    }
    size_t bh = ((size_t)head * 128 + d) * 2048 + st * 64 + jb;
    size_t bl = ((size_t)head * 128 + 64 + d) * 2048 + st * 64 + jb;
    *(bf16x8*)(Vt + bh)     = h0;
    *(bf16x8*)(Vt + bh + 8) = h1;
    *(bf16x8*)(Vt + bl)     = l0;
    *(bf16x8*)(Vt + bl + 8) = l1;
}

// ------------------------------------------------------------------
// attn_mfma: per block = (64-row i-tile, head). 4 waves x 16 rows.
// Two passes: (1) online row max/expsum via QK^T MFMA; (2) recompute S,
// write normalized attn (fp32), PV via MFMA -> z, store Az bf16 hi/lo.
// ------------------------------------------------------------------
__global__ __launch_bounds__(256) void attn_mfma(
    const __bf16* __restrict__ Qp, const __bf16* __restrict__ Kp,
    const __bf16* __restrict__ Vt, float* __restrict__ Attn,
    __bf16* __restrict__ Az)
{
    const int it = blockIdx.x, head = blockIdx.y;
    const int tid = (int)threadIdx.x;
    const int w = tid >> 6, lane = tid & 63;
    const int quad = lane >> 4, tl = lane & 15;
    const int i0 = it * 64;

    __shared__ __bf16 qs[64 * 136];  // Q tile rows: [hi(64)|lo(64)] + pad
    __shared__ __bf16 kb[64 * 136];  // K tile, same layout
    __shared__ __bf16 vt[128 * 72];  // V^T tile: row d2 (hi 0..63, lo 64..127), 64 j + pad
    __shared__ __bf16 ps[4 * 16 * 72]; // per-wave P staging (C->A layout)

    const __bf16* __restrict__ Qh = Qp + ((size_t)head * 2048 + i0) * 128;
    const __bf16* __restrict__ Kh = Kp + (size_t)head * 2048 * 128;
    const __bf16* __restrict__ Vh = Vt + (size_t)head * 128 * 2048;
    float* __restrict__ Ah = Attn + (size_t)head * ((size_t)2048 * 2048);

    // ---- stage Q tile (64 rows x 256 B), padded rows ----
    #pragma unroll
    for (int i = 0; i < 4; ++i) {
        int idx = i * 256 + tid;
        int r = idx >> 4, ch = idx & 15;
        bf16x8 t = *(const bf16x8*)(Qh + r * 128 + ch * 8);
        *(bf16x8*)(qs + r * 136 + ch * 8) = t;
    }
    __syncthreads();

    // resident A-fragments for QK^T (rows w*16+tl)
    const __bf16* qrow = qs + (w * 16 + tl) * 136;
    bf16x8 qhi0 = *(const bf16x8*)(qrow + quad * 8);
    bf16x8 qhi1 = *(const bf16x8*)(qrow + 32 + quad * 8);
    bf16x8 qlo0 = *(const bf16x8*)(qrow + 64 + quad * 8);
    bf16x8 qlo1 = *(const bf16x8*)(qrow + 96 + quad * 8);

    float m[4], l[4];
    #pragma unroll
    for (int r = 0; r < 4; ++r) { m[r] = -3.0e38f; l[r] = 0.0f; }

    // ---------- pass 1: stats ----------
    for (int jt = 0; jt <= it; ++jt) {
        __syncthreads();
        #pragma unroll
        for (int i = 0; i < 4; ++i) {
            int idx = i * 256 + tid;
            int r = idx >> 4, ch = idx & 15;
            bf16x8 t = *(const bf16x8*)(Kh + (size_t)(jt * 64 + r) * 128 + ch * 8);
            *(bf16x8*)(kb + r * 136 + ch * 8) = t;
        }
        __syncthreads();

        floatx4 S[4];
        #pragma unroll
        for (int sub = 0; sub < 4; ++sub) {
            const __bf16* kr = kb + (sub * 16 + tl) * 136;
            bf16x8 khi0 = *(const bf16x8*)(kr + quad * 8);
            bf16x8 khi1 = *(const bf16x8*)(kr + 32 + quad * 8);
            bf16x8 klo0 = *(const bf16x8*)(kr + 64 + quad * 8);
            bf16x8 klo1 = *(const bf16x8*)(kr + 96 + quad * 8);
            floatx4 s = (floatx4){0.f, 0.f, 0.f, 0.f};
            s = __builtin_amdgcn_mfma_f32_16x16x32_bf16(qhi0, khi0, s, 0, 0, 0);
            s = __builtin_amdgcn_mfma_f32_16x16x32_bf16(qhi1, khi1, s, 0, 0, 0);
            s = __builtin_amdgcn_mfma_f32_16x16x32_bf16(qhi0, klo0, s, 0, 0, 0);
            s = __builtin_amdgcn_mfma_f32_16x16x32_bf16(qhi1, klo1, s, 0, 0, 0);
            s = __builtin_amdgcn_mfma_f32_16x16x32_bf16(qlo0, khi0, s, 0, 0, 0);
            s = __builtin_amdgcn_mfma_f32_16x16x32_bf16(qlo1, khi1, s, 0, 0, 0);
            S[sub] = s;
        }
        const bool diag = (jt == it);
        #pragma unroll
        for (int reg = 0; reg < 4; ++reg) {
            const int irow = w * 16 + quad * 4 + reg;
            float sl[4];
            #pragma unroll
            for (int sub = 0; sub < 4; ++sub) {
                float lv = S[sub][reg] * 1000.0f;
                if (diag && (sub * 16 + tl > irow)) lv = -1.0e9f;
                sl[sub] = lv;
            }
            float mt = fmaxf(fmaxf(sl[0], sl[1]), fmaxf(sl[2], sl[3]));
            float mn = fmaxf(m[reg], mt);
            l[reg] = l[reg] * __expf(m[reg] - mn)
                   + __expf(sl[0]-mn) + __expf(sl[1]-mn)
                   + __expf(sl[2]-mn) + __expf(sl[3]-mn);
            m[reg] = mn;
        }
    }

    // reduce stats across the 16 tl lanes (same quad = same rows)
    #pragma unroll
    for (int reg = 0; reg < 4; ++reg) {
        #pragma unroll
        for (int mk = 8; mk >= 1; mk >>= 1) {
            float mo = __shfl_xor(m[reg], mk);
            float lo = __shfl_xor(l[reg], mk);
            float mn = fmaxf(m[reg], mo);
            l[reg] = l[reg] * __expf(m[reg] - mn) + lo * __expf(mo - mn);
            m[reg] = mn;
        }
    }
    float inv_l[4];
    #pragma unroll
    for (int reg = 0; reg < 4; ++reg) inv_l[reg] = 1.0f / l[reg];

    // ---------- pass 2 ----------
    floatx4 zacc[4];
    #pragma unroll
    for (int t = 0; t < 4; ++t) zacc[t] = (floatx4){0.f, 0.f, 0.f, 0.f};
    __bf16* psw = ps + w * 16 * 72;

    for (int jt = 0; jt < 32; ++jt) {
        if (jt > it) {   // masked tile: exact zeros, coalesced float4
            float4 z4 = make_float4(0.f, 0.f, 0.f, 0.f);
            #pragma unroll
            for (int reg = 0; reg < 4; ++reg)
                *(float4*)(Ah + (size_t)(i0 + w * 16 + quad * 4 + reg) * 2048
                              + jt * 64 + tl * 4) = z4;
            continue;
        }
        __syncthreads();
        #pragma unroll
        for (int i = 0; i < 4; ++i) {
            int idx = i * 256 + tid;
            int r = idx >> 4, ch = idx & 15;
            bf16x8 t = *(const bf16x8*)(Kh + (size_t)(jt * 64 + r) * 128 + ch * 8);
            *(bf16x8*)(kb + r * 136 + ch * 8) = t;
        }
        #pragma unroll
        for (int i = 0; i < 4; ++i) {
            int idx = i * 256 + tid;
            int r = idx >> 3, ch = idx & 7;
            bf16x8 t = *(const bf16x8*)(Vh + (size_t)r * 2048 + jt * 64 + ch * 8);
            *(bf16x8*)(vt + r * 72 + ch * 8) = t;
        }
        __syncthreads();

        floatx4 S[4];
        #pragma unroll
        for (int sub = 0; sub < 4; ++sub) {
            const __bf16* kr = kb + (sub * 16 + tl) * 136;
            bf16x8 khi0 = *(const bf16x8*)(kr + quad * 8);
            bf16x8 khi1 = *(const bf16x8*)(kr + 32 + quad * 8);
            bf16x8 klo0 = *(const bf16x8*)(kr + 64 + quad * 8);
            bf16x8 klo1 = *(const bf16x8*)(kr + 96 + quad * 8);
            floatx4 s = (floatx4){0.f, 0.f, 0.f, 0.f};
            s = __builtin_amdgcn_mfma_f32_16x16x32_bf16(qhi0, khi0, s, 0, 0, 0);
            s = __builtin_amdgcn_mfma_f32_16x16x32_bf16(qhi1, khi1, s, 0, 0, 0);
            s = __builtin_amdgcn_mfma_f32_16x16x32_bf16(qhi0, klo0, s, 0, 0, 0);
            s = __builtin_amdgcn_mfma_f32_16x16x32_bf16(qhi1, klo1, s, 0, 0, 0);
            s = __builtin_amdgcn_mfma_f32_16x16x32_bf16(qlo0, khi0, s, 0, 0, 0);
            s = __builtin_amdgcn_mfma_f32_16x16x32_bf16(qlo1, khi1, s, 0, 0, 0);
            S[sub] = s;
        }
        const bool diag = (jt == it);
        #pragma unroll
        for (int reg = 0; reg < 4; ++reg) {
            const int irow = w * 16 + quad * 4 + reg;
            #pragma unroll
            for (int sub = 0; sub < 4; ++sub) {
                float lv = S[sub][reg] * 1000.0f;
                if (diag && (sub * 16 + tl > irow)) lv = -1.0e9f;
                float p = __expf(lv - m[reg]) * inv_l[reg];
                Ah[(size_t)(i0 + irow) * 2048 + jt * 64 + sub * 16 + tl] = p;
                psw[(quad * 4 + reg) * 72 + sub * 16 + tl] = (__bf16)p;
            }
        }
        // P A-fragments (per-wave private LDS -> no barrier needed)
        bf16x8 p0 = *(const bf16x8*)(psw + tl * 72 + quad * 8);
        bf16x8 p1 = *(const bf16x8*)(psw + tl * 72 + 32 + quad * 8);
        #pragma unroll
        for (int t = 0; t < 4; ++t) {
            const __bf16* vh0 = vt + (t * 16 + tl) * 72;         // V hi row d
            const __bf16* vl0 = vt + (64 + t * 16 + tl) * 72;    // V lo row d
            bf16x8 vhi0 = *(const bf16x8*)(vh0 + quad * 8);
            bf16x8 vhi1 = *(const bf16x8*)(vh0 + 32 + quad * 8);
            bf16x8 vlo0 = *(const bf16x8*)(vl0 + quad * 8);
            bf16x8 vlo1 = *(const bf16x8*)(vl0 + 32 + quad * 8);
            zacc[t] = __builtin_amdgcn_mfma_f32_16x16x32_bf16(p0, vhi0, zacc[t], 0, 0, 0);
            zacc[t] = __builtin_amdgcn_mfma_f32_16x16x32_bf16(p1, vhi1, zacc[t], 0, 0, 0);
            zacc[t] = __builtin_amdgcn_mfma_f32_16x16x32_bf16(p0, vlo0, zacc[t], 0, 0, 0);
            zacc[t] = __builtin_amdgcn_mfma_f32_16x16x32_bf16(p1, vlo1, zacc[t], 0, 0, 0);
        }
    }

    // epilogue: z -> Az bf16 hi/lo (A-layout for out-GEMM)
    const int b = head >> 4, h = head & 15;
    #pragma unroll
    for (int reg = 0; reg < 4; ++reg) {
        const size_t R = (size_t)b * 2048 + i0 + w * 16 + quad * 4 + reg;
        #pragma unroll
        for (int t = 0; t < 4; ++t) {
            float x = zacc[t][reg];
            __bf16 hh = (__bf16)x;
            Az[R * 2048 + h * 64 + t * 16 + tl]        = hh;
            Az[R * 2048 + 1024 + h * 64 + t * 16 + tl] = (__bf16)(x - (float)hh);
        }
    }
}

// ------------------------------------------------------------------
extern "C" void kernel_launch(void* const* d_in, const int* in_sizes, int n_in,
                              void* d_out, int out_size, void* d_ws, size_t ws_size,
                              hipStream_t stream) {
    (void)in_sizes; (void)n_in; (void)out_size;
    const float* q  = (const float*)d_in[0];
    const float* k  = (const float*)d_in[1];
    const float* v  = (const float*)d_in[2];
    const float* Wq = (const float*)d_in[4];  const float* bq = (const float*)d_in[5];
    const float* Wk = (const float*)d_in[6];  const float* bk = (const float*)d_in[7];
    const float* Wv = (const float*)d_in[8];  const float* bv = (const float*)d_in[9];
    const float* Wz = (const float*)d_in[10]; const float* bz = (const float*)d_in[11];

    float* out0 = (float*)d_out;               // (2,2048,1024)
    float* attn = out0 + 4194304;              // (2,16,2048,2048) = 512 MB

    // Scratch in the not-yet-written attn region:
    float*  PT0 = attn;                                   // 3 x 4M floats
    __bf16* Ap0 = (__bf16*)(attn + 12582912);             // 3 x 4096x2048 bf16
    __bf16* Bp0 = (__bf16*)(attn + 12582912 + 12582912);  // 3 x 1024x2048 bf16

    // Wz split lives in Wq's buffer (consumed before this is written).
    __bf16* Bpz = (__bf16*)d_in[4];

    // Qp/Kp/Vt/Az bf16, 16 MB each. Prefer ws (64 MB); fallback clobbers
    // consumed inputs (restored by harness before every launch).
    __bf16 *Qp, *Kp, *Vtp, *Az;
    if (ws_size >= (size_t)67108864) {
        __bf16* ws = (__bf16*)d_ws;
        Qp = ws; Kp = ws + 8388608; Vtp = ws + 16777216; Az = ws + 25165824;
    } else {
        Qp = (__bf16*)d_in[0]; Kp = (__bf16*)d_in[1]; Vtp = (__bf16*)d_in[2];
        Az = (__bf16*)d_ws;
    }

    split_a <<<dim3(4096, 1, 3), 256, 0, stream>>>(q, k, v, Ap0);
    split_bt<<<dim3(16, 16, 3), 256, 0, stream>>>(Wq, Wk, Wv, Bp0, 1024ull*2048);

    gemm_split<<<dim3(8, 32, 3), 256, 0, stream>>>(Ap0, Bp0, bq, bk, bv, PT0, 1);

    gather_qk  <<<16384, 256, 0, stream>>>(PT0,           Qp);
    gather_qk  <<<16384, 256, 0, stream>>>(PT0 + 4194304, Kp);
    v_transpose<<<dim3(32, 32), 256, 0, stream>>>(PT0 + 8388608, Vtp);

    split_bt<<<dim3(16, 16, 1), 256, 0, stream>>>(Wz, Wz, Wz, Bpz, 0);

    attn_mfma<<<dim3(32, 32), 256, 0, stream>>>(Qp, Kp, Vtp, attn, Az);

    gemm_split<<<dim3(8, 32, 1), 256, 0, stream>>>(Az, Bpz, bz, bz, bz, out0, 0);
}